// Round 5
// baseline (204.358 us; speedup 1.0000x reference)
//
#include <hip/hip_runtime.h>
#include <hip/hip_cooperative_groups.h>

namespace cg = cooperative_groups;

#define NBINS 128
#define DCOLS 512
#define NBANK 16
#define RPB   16    // rows per block (one-shot)
#define F4PT  8     // float4 loads per thread
#define NHB   32    // histogram blocks (32 * 256 = 8192 targets)
#define GRID_BLKS 512

// ws layout (bytes):
//   [0, 32768)      float ubank[16][512]
//   [32768, 65536)  float vbank[16][512]   (contiguous with ubank)
//   [65536, 81920)  int   hist32[32][128]  (per-block slices, plain stores)
//   [81920, 81936)  float scal[4]          (T, P, Q)

__global__ void __launch_bounds__(256) fused(const float* __restrict__ x,
                                             const int* __restrict__ tgt,
                                             int n, int d,
                                             float* __restrict__ ubank,
                                             float* __restrict__ vbank,
                                             int* __restrict__ hist32,
                                             float* __restrict__ scal,
                                             float* __restrict__ out) {
    cg::grid_group grid = cg::this_grid();
    const int tid = threadIdx.x;
    const int bid = blockIdx.x;
    const int half = tid >> 7;
    const int j    = tid & 127;

    __shared__ int   hsh[NBINS];
    __shared__ float crow[RPB];
    __shared__ float ush[DCOLS];
    __shared__ float vsh[DCOLS];
    __shared__ float red[4][4];

    // ---- phase A0: issue all 8 independent x loads immediately (overlap everything) ----
    float4 xv[F4PT];
    const float4* xf4 = (const float4*)x;
    const size_t base = (size_t)bid * (RPB * DCOLS / 4);
    const bool has_rows = (bid * RPB + RPB <= n);
    if (has_rows) {
        #pragma unroll
        for (int k = 0; k < F4PT; ++k)
            xv[k] = xf4[base + (size_t)k * 256 + tid];
    }

    // ---- phase A1: zero ubank/vbank/scal slices (plain stores, disjoint) ----
    {
        int gt = bid * 256 + tid;
        if (gt < 2 * NBANK * DCOLS) ubank[gt] = 0.f;   // covers ubank + vbank
        if (gt < 4) scal[gt] = 0.f;
    }

    // ---- phase A2: blocks 0..31 build private histogram slices (no global atomics) ----
    if (bid < NHB) {
        if (tid < NBINS) hsh[tid] = 0;
        __syncthreads();
        int i = bid * 256 + tid;
        if (i < n) atomicAdd(&hsh[tgt[i] & (NBINS - 1)], 1);
        __syncthreads();
        if (tid < NBINS) hist32[bid * NBINS + tid] = hsh[tid];
    }

    grid.sync();

    // ---- phase B: per-row class counts, then one-shot accumulate ----
    if (tid < RPB) {
        int row = bid * RPB + tid;
        float c = 0.f;
        if (row < n) {
            int g = tgt[row] & (NBINS - 1);
            int s = 0;
            #pragma unroll
            for (int b = 0; b < NHB; ++b) s += hist32[b * NBINS + g];
            c = (float)s;
        }
        crow[tid] = c;
    }
    __syncthreads();

    float t_acc = 0.f, p_acc = 0.f, q_acc = 0.f;
    float4 ua = make_float4(0.f, 0.f, 0.f, 0.f);
    float4 va = make_float4(0.f, 0.f, 0.f, 0.f);
    if (has_rows) {
        #pragma unroll
        for (int k = 0; k < F4PT; ++k) {
            float  c = crow[2 * k + half];
            float4 v = xv[k];
            float sq = v.x*v.x + v.y*v.y + v.z*v.z + v.w*v.w;
            float sm = v.x + v.y + v.z + v.w;
            t_acc += sq;
            p_acc += c * sq;
            q_acc += c * sm;
            ua.x += v.x;     ua.y += v.y;     ua.z += v.z;     ua.w += v.w;
            va.x += c * v.x; va.y += c * v.y; va.z += c * v.z; va.w += c * v.w;
        }
    }

    // u/v block reduction across the two halves
    if (half == 0) {
        ush[4*j+0] = ua.x; ush[4*j+1] = ua.y; ush[4*j+2] = ua.z; ush[4*j+3] = ua.w;
        vsh[4*j+0] = va.x; vsh[4*j+1] = va.y; vsh[4*j+2] = va.z; vsh[4*j+3] = va.w;
    }
    __syncthreads();
    if (half == 1) {
        ush[4*j+0] += ua.x; ush[4*j+1] += ua.y; ush[4*j+2] += ua.z; ush[4*j+3] += ua.w;
        vsh[4*j+0] += va.x; vsh[4*j+1] += va.y; vsh[4*j+2] += va.z; vsh[4*j+3] += va.w;
    }
    __syncthreads();

    // banked HW fp32 atomics: 512/16 = 32 adds per address
    {
        const int cb = (bid & (NBANK - 1)) * DCOLS;
        unsafeAtomicAdd(&ubank[cb + 2*tid + 0], ush[2*tid + 0]);
        unsafeAtomicAdd(&ubank[cb + 2*tid + 1], ush[2*tid + 1]);
        unsafeAtomicAdd(&vbank[cb + 2*tid + 0], vsh[2*tid + 0]);
        unsafeAtomicAdd(&vbank[cb + 2*tid + 1], vsh[2*tid + 1]);
    }

    // scalar (T,P,Q) reduction
    for (int off = 32; off > 0; off >>= 1) {
        t_acc += __shfl_down(t_acc, off);
        p_acc += __shfl_down(p_acc, off);
        q_acc += __shfl_down(q_acc, off);
    }
    const int wave = tid >> 6, lane = tid & 63;
    if (lane == 0) { red[0][wave] = t_acc; red[1][wave] = p_acc; red[2][wave] = q_acc; }
    __syncthreads();
    if (tid == 0) {
        unsafeAtomicAdd(&scal[0], red[0][0] + red[0][1] + red[0][2] + red[0][3]);
        unsafeAtomicAdd(&scal[1], red[1][0] + red[1][1] + red[1][2] + red[1][3]);
        unsafeAtomicAdd(&scal[2], red[2][0] + red[2][1] + red[2][2] + red[2][3]);
    }

    grid.sync();

    // ---- phase C: block 0 finalizes ----
    if (bid != 0) return;

    float uu = 0.f, us = 0.f, uv = 0.f, wc = 0.f;
    for (int k = tid; k < DCOLS; k += 256) {
        float uf = 0.f, vf = 0.f;
        #pragma unroll
        for (int b = 0; b < NBANK; ++b) {
            uf += ubank[b * DCOLS + k];
            vf += vbank[b * DCOLS + k];
        }
        uu += uf * uf;
        us += uf;
        uv += uf * vf;
    }
    if (tid < NBINS) {
        int s = 0;
        #pragma unroll
        for (int b = 0; b < NHB; ++b) s += hist32[b * NBINS + tid];
        float h = (float)s;
        wc = h * h;
    }

    for (int off = 32; off > 0; off >>= 1) {
        uu += __shfl_down(uu, off);
        us += __shfl_down(us, off);
        uv += __shfl_down(uv, off);
        wc += __shfl_down(wc, off);
    }
    __syncthreads();   // red[] reuse
    if (lane == 0) { red[0][wave] = uu; red[1][wave] = us; red[2][wave] = uv; red[3][wave] = wc; }
    __syncthreads();
    if (tid == 0) {
        double UU = 0, US = 0, UV = 0, WC = 0;
        for (int w = 0; w < 4; ++w) {
            UU += red[0][w]; US += red[1][w]; UV += red[2][w]; WC += red[3][w];
        }
        const double T = scal[0], P = scal[1], Q = scal[2];
        const double N = (double)n, Dd = (double)d, eps = 1e-6;
        double Ssum = 2.0 * N * T - 2.0 * UU + N * N * Dd * eps * eps;
        double Anum = N * P + T * WC - 2.0 * UV
                    + 2.0 * eps * (N * Q - US * WC) + N * Dd * eps * eps * WC;
        double a = Anum / (N * WC);
        double b = (N * Ssum - Anum) / (N * (N * N - WC));
        out[0] = (float)(-a / b - b / a);
    }
}

extern "C" void kernel_launch(void* const* d_in, const int* in_sizes, int n_in,
                              void* d_out, int out_size, void* d_ws, size_t ws_size,
                              hipStream_t stream) {
    const float* x   = (const float*)d_in[0];
    const int*   tgt = (const int*)d_in[1];
    float*       out = (float*)d_out;

    int n = in_sizes[1];          // 8192
    int d = in_sizes[0] / n;      // 512

    char*  ws     = (char*)d_ws;
    float* ubank  = (float*)ws;                                   // 32 KB
    float* vbank  = (float*)(ws + NBANK * DCOLS * 4);             // 32 KB
    int*   hist32 = (int*)  (ws + 2 * NBANK * DCOLS * 4);         // 16 KB
    float* scal   = (float*)(ws + 2 * NBANK * DCOLS * 4 + NHB * NBINS * 4); // 16 B

    void* args[] = {(void*)&x, (void*)&tgt, (void*)&n, (void*)&d,
                    (void*)&ubank, (void*)&vbank, (void*)&hist32,
                    (void*)&scal, (void*)&out};
    hipLaunchCooperativeKernel((void*)fused, dim3(GRID_BLKS), dim3(256),
                               args, 0, stream);
}

// Round 6
// 108.813 us; speedup vs baseline: 1.8781x; 1.8781x over previous
//
#include <hip/hip_runtime.h>

#define DCOLS 512
#define NBANK 16
#define RPB   16    // rows per block (one-shot)
#define F4PT  8     // float4 loads per thread

// ws layout (bytes):
//   [0, 32768)      float ubank[16][512]
//   [32768, 65536)  float vbank[16][512]
//   [65536, 65552)  float scal[4]   (T, P, Q, WC)
// memset range: [0, 65552)

// ---------------- main pass: one dispatch does hist-free counts + streaming ----------------
__global__ __launch_bounds__(256) void main_pass(const float* __restrict__ x,
                                                 const int* __restrict__ tgt,
                                                 float* __restrict__ ubank,
                                                 float* __restrict__ vbank,
                                                 float* __restrict__ scal) {
    const int tid  = threadIdx.x;
    const int bid  = blockIdx.x;
    const int half = tid >> 7;     // row parity within the float4 tiling
    const int j    = tid & 127;    // float4 column group

    // ---- (1) block row labels -> SGPRs (uniform) ----
    int lab[RPB];
    #pragma unroll
    for (int l = 0; l < RPB; ++l)
        lab[l] = __builtin_amdgcn_readfirstlane(tgt[bid * RPB + l]);

    // ---- (2) 32 targets per thread, coalesced int4 (8192 total per block) ----
    int4 tv[8];
    const int4* t4 = (const int4*)tgt;
    #pragma unroll
    for (int k = 0; k < 8; ++k)
        tv[k] = t4[k * 256 + tid];

    // ---- (3) the block's 16 rows of x: 8 independent float4 loads ----
    float4 xv[F4PT];
    const float4* xf4 = (const float4*)x;
    const size_t base = (size_t)bid * (RPB * DCOLS / 4);
    #pragma unroll
    for (int k = 0; k < F4PT; ++k)
        xv[k] = xf4[base + (size_t)k * 256 + tid];

    // pin: nothing moves above, loads can't sink below
    __builtin_amdgcn_sched_barrier(0);

    // ---- (4) ballot-count the 16 row labels over all 8192 targets ----
    // (uses only tv => waits vmcnt(8); xv loads remain in flight)
    int cnt[RPB];
    #pragma unroll
    for (int l = 0; l < RPB; ++l) cnt[l] = 0;
    #pragma unroll
    for (int k = 0; k < 8; ++k) {
        #pragma unroll
        for (int c = 0; c < 4; ++c) {
            const int tval = (c == 0) ? tv[k].x : (c == 1) ? tv[k].y
                           : (c == 2) ? tv[k].z : tv[k].w;
            #pragma unroll
            for (int l = 0; l < RPB; ++l)
                cnt[l] += (int)__popcll(__ballot(tval == lab[l]));
        }
    }

    // per-wave counts are uniform; combine 4 waves in LDS
    __shared__ int   cw[4][RPB];
    __shared__ float crow[RPB];
    const int wave = tid >> 6, lane = tid & 63;
    if (lane == 0) {
        #pragma unroll
        for (int l = 0; l < RPB; ++l) cw[wave][l] = cnt[l];
    }
    __syncthreads();
    if (tid < RPB)
        crow[tid] = (float)(cw[0][tid] + cw[1][tid] + cw[2][tid] + cw[3][tid]);
    __syncthreads();

    // ---- (5) accumulate: row(k) = bid*16 + 2k + half ----
    float t_acc = 0.f, p_acc = 0.f, q_acc = 0.f;
    float4 ua = make_float4(0.f, 0.f, 0.f, 0.f);
    float4 va = make_float4(0.f, 0.f, 0.f, 0.f);
    #pragma unroll
    for (int k = 0; k < F4PT; ++k) {
        float  c = crow[2 * k + half];
        float4 v = xv[k];
        float sq = v.x*v.x + v.y*v.y + v.z*v.z + v.w*v.w;
        float sm = v.x + v.y + v.z + v.w;
        t_acc += sq;
        p_acc += c * sq;
        q_acc += c * sm;
        ua.x += v.x;     ua.y += v.y;     ua.z += v.z;     ua.w += v.w;
        va.x += c * v.x; va.y += c * v.y; va.z += c * v.z; va.w += c * v.w;
    }

    // ---- (6) u/v block reduction across the two halves ----
    __shared__ float ush[DCOLS];
    __shared__ float vsh[DCOLS];
    if (half == 0) {
        ush[4*j+0] = ua.x; ush[4*j+1] = ua.y; ush[4*j+2] = ua.z; ush[4*j+3] = ua.w;
        vsh[4*j+0] = va.x; vsh[4*j+1] = va.y; vsh[4*j+2] = va.z; vsh[4*j+3] = va.w;
    }
    __syncthreads();
    if (half == 1) {
        ush[4*j+0] += ua.x; ush[4*j+1] += ua.y; ush[4*j+2] += ua.z; ush[4*j+3] += ua.w;
        vsh[4*j+0] += va.x; vsh[4*j+1] += va.y; vsh[4*j+2] += va.z; vsh[4*j+3] += va.w;
    }
    __syncthreads();

    // ---- (7) banked HW fp32 atomics: 512/16 = 32 adds per address ----
    const int cb = (bid & (NBANK - 1)) * DCOLS;
    unsafeAtomicAdd(&ubank[cb + 2*tid + 0], ush[2*tid + 0]);
    unsafeAtomicAdd(&ubank[cb + 2*tid + 1], ush[2*tid + 1]);
    unsafeAtomicAdd(&vbank[cb + 2*tid + 0], vsh[2*tid + 0]);
    unsafeAtomicAdd(&vbank[cb + 2*tid + 1], vsh[2*tid + 1]);

    // ---- (8) scalar reduction: T, P, Q (+ WC = sum of crow, exact int in fp32) ----
    for (int off = 32; off > 0; off >>= 1) {
        t_acc += __shfl_down(t_acc, off);
        p_acc += __shfl_down(p_acc, off);
        q_acc += __shfl_down(q_acc, off);
    }
    __shared__ float red[3][4];
    if (lane == 0) { red[0][wave] = t_acc; red[1][wave] = p_acc; red[2][wave] = q_acc; }
    __syncthreads();
    if (tid == 0) {
        float csum = 0.f;
        #pragma unroll
        for (int l = 0; l < RPB; ++l) csum += crow[l];
        unsafeAtomicAdd(&scal[0], red[0][0] + red[0][1] + red[0][2] + red[0][3]);
        unsafeAtomicAdd(&scal[1], red[1][0] + red[1][1] + red[1][2] + red[1][3]);
        unsafeAtomicAdd(&scal[2], red[2][0] + red[2][1] + red[2][2] + red[2][3]);
        unsafeAtomicAdd(&scal[3], csum);
    }
}

// ---------------- final: UU, US, UV + closed form ----------------
__global__ __launch_bounds__(256) void finalk(const float* __restrict__ scal,
                                              const float* __restrict__ ubank,
                                              const float* __restrict__ vbank,
                                              int n, int d,
                                              float* __restrict__ out) {
    const int tid = threadIdx.x;
    float uu = 0.f, us = 0.f, uv = 0.f;
    #pragma unroll
    for (int c = tid; c < DCOLS; c += 256) {
        float uf = 0.f, vf = 0.f;
        #pragma unroll
        for (int b = 0; b < NBANK; ++b) {
            uf += ubank[b * DCOLS + c];
            vf += vbank[b * DCOLS + c];
        }
        uu += uf * uf;
        us += uf;
        uv += uf * vf;
    }
    for (int off = 32; off > 0; off >>= 1) {
        uu += __shfl_down(uu, off);
        us += __shfl_down(us, off);
        uv += __shfl_down(uv, off);
    }
    __shared__ float red[3][4];
    const int wave = tid >> 6, lane = tid & 63;
    if (lane == 0) { red[0][wave] = uu; red[1][wave] = us; red[2][wave] = uv; }
    __syncthreads();
    if (tid == 0) {
        double UU = 0, US = 0, UV = 0;
        for (int w = 0; w < 4; ++w) { UU += red[0][w]; US += red[1][w]; UV += red[2][w]; }
        const double T = scal[0], P = scal[1], Q = scal[2], WC = scal[3];
        const double N = (double)n, Dd = (double)d, eps = 1e-6;
        double Ssum = 2.0 * N * T - 2.0 * UU + N * N * Dd * eps * eps;
        double Anum = N * P + T * WC - 2.0 * UV
                    + 2.0 * eps * (N * Q - US * WC) + N * Dd * eps * eps * WC;
        double a = Anum / (N * WC);
        double b = (N * Ssum - Anum) / (N * (N * N - WC));
        out[0] = (float)(-a / b - b / a);
    }
}

extern "C" void kernel_launch(void* const* d_in, const int* in_sizes, int n_in,
                              void* d_out, int out_size, void* d_ws, size_t ws_size,
                              hipStream_t stream) {
    const float* x   = (const float*)d_in[0];
    const int*   tgt = (const int*)d_in[1];
    float*       out = (float*)d_out;

    const int n = in_sizes[1];          // 8192
    const int d = in_sizes[0] / n;      // 512

    char*  ws    = (char*)d_ws;
    float* ubank = (float*)ws;                           // 32 KB
    float* vbank = (float*)(ws + NBANK * DCOLS * 4);     // 32 KB
    float* scal  = (float*)(ws + 2 * NBANK * DCOLS * 4); // 16 B

    hipMemsetAsync(d_ws, 0, 2 * NBANK * DCOLS * 4 + 16, stream);
    main_pass<<<n / RPB, 256, 0, stream>>>(x, tgt, ubank, vbank, scal);
    finalk   <<<1,       256, 0, stream>>>(scal, ubank, vbank, n, d, out);
}

// Round 7
// 91.971 us; speedup vs baseline: 2.2220x; 1.1831x over previous
//
#include <hip/hip_runtime.h>

#define NBINS 128
#define DCOLS 512
#define NBANK 16
#define RPB   16    // rows per block (one-shot)
#define F4PT  8     // float4 chunks per thread

// ws layout (bytes):
//   [0, 32768)      float ubank[16][512]
//   [32768, 65536)  float vbank[16][512]
//   [65536, 66048)  int   hist[128]
//   [66048, 66064)  float scal[4]   (T, P, Q)

// ---------------- kernel 1: zero ws + histogram (single block) ----------------
__global__ __launch_bounds__(1024) void setup_kernel(const int* __restrict__ tgt,
                                                     int n,
                                                     float* __restrict__ ubank,
                                                     int* __restrict__ hist,
                                                     float* __restrict__ scal) {
    const int tid = threadIdx.x;

    // zero ubank+vbank (contiguous 2*16*512 floats = 8192 float4s)
    float4* b4 = (float4*)ubank;
    #pragma unroll
    for (int k = 0; k < 8; ++k)
        b4[k * 1024 + tid] = make_float4(0.f, 0.f, 0.f, 0.f);
    if (tid < 4) scal[tid] = 0.f;

    __shared__ int h[NBINS];
    if (tid < NBINS) h[tid] = 0;
    __syncthreads();
    for (int i = tid; i < n; i += 1024)
        atomicAdd(&h[tgt[i] & (NBINS - 1)], 1);
    __syncthreads();
    if (tid < NBINS) hist[tid] = h[tid];
}

// ---------------- kernel 2: one-shot main pass with LDS staging ----------------
__global__ __launch_bounds__(256) void main_pass(const float* __restrict__ x,
                                                 const int* __restrict__ tgt,
                                                 const int* __restrict__ hist,
                                                 float* __restrict__ ubank,
                                                 float* __restrict__ vbank,
                                                 float* __restrict__ scal) {
    const int tid  = threadIdx.x;
    const int bid  = blockIdx.x;
    const int half = tid >> 7;
    const int j    = tid & 127;
    const int wave = tid >> 6, lane = tid & 63;

    __shared__ float xbuf[RPB * DCOLS];   // 32 KB: the block's 16 rows
    __shared__ float crow[RPB];
    __shared__ float ush[DCOLS];
    __shared__ float vsh[DCOLS];
    __shared__ float red[3][4];

    // ---- stage the block's 32 KB of x into LDS: 8 async 16B copies/thread,
    //      all outstanding at once (cannot sink — no register consumer) ----
    const float4* x4 = (const float4*)x + (size_t)bid * (RPB * DCOLS / 4);
    #pragma unroll
    for (int k = 0; k < F4PT; ++k) {
        // wave-uniform LDS base; lane data lands at base + lane*16
        float* ldsbase = &xbuf[(k * 256 + 64 * wave) * 4];
        __builtin_amdgcn_global_load_lds(
            (const __attribute__((address_space(1))) void*)(x4 + k * 256 + tid),
            (__attribute__((address_space(3))) void*)ldsbase,
            16, 0, 0);
    }

    // ---- per-row class counts (overlaps the staging stream) ----
    if (tid < RPB)
        crow[tid] = (float)hist[tgt[bid * RPB + tid] & (NBINS - 1)];

    __syncthreads();   // drains vmcnt(0) + barrier: xbuf and crow ready

    // ---- accumulate: row(k) = bid*16 + 2k + half, cols 4j..4j+3 ----
    float t_acc = 0.f, p_acc = 0.f, q_acc = 0.f;
    float4 ua = make_float4(0.f, 0.f, 0.f, 0.f);
    float4 va = make_float4(0.f, 0.f, 0.f, 0.f);
    #pragma unroll
    for (int k = 0; k < F4PT; ++k) {
        float  c = crow[2 * k + half];
        float4 v = ((const float4*)xbuf)[k * 256 + tid];
        float sq = v.x*v.x + v.y*v.y + v.z*v.z + v.w*v.w;
        float sm = v.x + v.y + v.z + v.w;
        t_acc += sq;
        p_acc += c * sq;
        q_acc += c * sm;
        ua.x += v.x;     ua.y += v.y;     ua.z += v.z;     ua.w += v.w;
        va.x += c * v.x; va.y += c * v.y; va.z += c * v.z; va.w += c * v.w;
    }

    // ---- u/v block reduction across the two halves ----
    if (half == 0) {
        ush[4*j+0] = ua.x; ush[4*j+1] = ua.y; ush[4*j+2] = ua.z; ush[4*j+3] = ua.w;
        vsh[4*j+0] = va.x; vsh[4*j+1] = va.y; vsh[4*j+2] = va.z; vsh[4*j+3] = va.w;
    }
    __syncthreads();
    if (half == 1) {
        ush[4*j+0] += ua.x; ush[4*j+1] += ua.y; ush[4*j+2] += ua.z; ush[4*j+3] += ua.w;
        vsh[4*j+0] += va.x; vsh[4*j+1] += va.y; vsh[4*j+2] += va.z; vsh[4*j+3] += va.w;
    }
    __syncthreads();

    // ---- banked HW fp32 atomics: 512/16 = 32 adds per address ----
    const int cb = (bid & (NBANK - 1)) * DCOLS;
    unsafeAtomicAdd(&ubank[cb + 2*tid + 0], ush[2*tid + 0]);
    unsafeAtomicAdd(&ubank[cb + 2*tid + 1], ush[2*tid + 1]);
    unsafeAtomicAdd(&vbank[cb + 2*tid + 0], vsh[2*tid + 0]);
    unsafeAtomicAdd(&vbank[cb + 2*tid + 1], vsh[2*tid + 1]);

    // ---- scalar (T,P,Q) reduction ----
    for (int off = 32; off > 0; off >>= 1) {
        t_acc += __shfl_down(t_acc, off);
        p_acc += __shfl_down(p_acc, off);
        q_acc += __shfl_down(q_acc, off);
    }
    if (lane == 0) { red[0][wave] = t_acc; red[1][wave] = p_acc; red[2][wave] = q_acc; }
    __syncthreads();
    if (tid == 0) {
        unsafeAtomicAdd(&scal[0], red[0][0] + red[0][1] + red[0][2] + red[0][3]);
        unsafeAtomicAdd(&scal[1], red[1][0] + red[1][1] + red[1][2] + red[1][3]);
        unsafeAtomicAdd(&scal[2], red[2][0] + red[2][1] + red[2][2] + red[2][3]);
    }
}

// ---------------- kernel 3: UU, US, UV, WC + closed form ----------------
__global__ __launch_bounds__(256) void finalk(const int* __restrict__ hist,
                                              const float* __restrict__ scal,
                                              const float* __restrict__ ubank,
                                              const float* __restrict__ vbank,
                                              int n, int d,
                                              float* __restrict__ out) {
    const int tid = threadIdx.x;
    float uu = 0.f, us = 0.f, uv = 0.f, wc = 0.f;
    #pragma unroll
    for (int c = tid; c < DCOLS; c += 256) {
        float uf = 0.f, vf = 0.f;
        #pragma unroll
        for (int b = 0; b < NBANK; ++b) {
            uf += ubank[b * DCOLS + c];
            vf += vbank[b * DCOLS + c];
        }
        uu += uf * uf;
        us += uf;
        uv += uf * vf;
    }
    if (tid < NBINS) { float h = (float)hist[tid]; wc = h * h; }

    for (int off = 32; off > 0; off >>= 1) {
        uu += __shfl_down(uu, off);
        us += __shfl_down(us, off);
        uv += __shfl_down(uv, off);
        wc += __shfl_down(wc, off);
    }
    __shared__ float red[4][4];
    const int wave = tid >> 6, lane = tid & 63;
    if (lane == 0) { red[0][wave] = uu; red[1][wave] = us; red[2][wave] = uv; red[3][wave] = wc; }
    __syncthreads();
    if (tid == 0) {
        double UU = 0, US = 0, UV = 0, WC = 0;
        for (int w = 0; w < 4; ++w) {
            UU += red[0][w]; US += red[1][w]; UV += red[2][w]; WC += red[3][w];
        }
        const double T = scal[0], P = scal[1], Q = scal[2];
        const double N = (double)n, Dd = (double)d, eps = 1e-6;
        double Ssum = 2.0 * N * T - 2.0 * UU + N * N * Dd * eps * eps;
        double Anum = N * P + T * WC - 2.0 * UV
                    + 2.0 * eps * (N * Q - US * WC) + N * Dd * eps * eps * WC;
        double a = Anum / (N * WC);
        double b = (N * Ssum - Anum) / (N * (N * N - WC));
        out[0] = (float)(-a / b - b / a);
    }
}

extern "C" void kernel_launch(void* const* d_in, const int* in_sizes, int n_in,
                              void* d_out, int out_size, void* d_ws, size_t ws_size,
                              hipStream_t stream) {
    const float* x   = (const float*)d_in[0];
    const int*   tgt = (const int*)d_in[1];
    float*       out = (float*)d_out;

    const int n = in_sizes[1];          // 8192
    const int d = in_sizes[0] / n;      // 512

    char*  ws    = (char*)d_ws;
    float* ubank = (float*)ws;                                   // 32 KB
    float* vbank = (float*)(ws + NBANK * DCOLS * 4);             // 32 KB
    int*   hist  = (int*)  (ws + 2 * NBANK * DCOLS * 4);         // 512 B
    float* scal  = (float*)(ws + 2 * NBANK * DCOLS * 4 + NBINS * 4); // 16 B

    setup_kernel<<<1,       1024, 0, stream>>>(tgt, n, ubank, hist, scal);
    main_pass  <<<n / RPB,  256,  0, stream>>>(x, tgt, hist, ubank, vbank, scal);
    finalk     <<<1,        256,  0, stream>>>(hist, scal, ubank, vbank, n, d, out);
}

// Round 8
// 73.485 us; speedup vs baseline: 2.7809x; 1.2515x over previous
//
#include <hip/hip_runtime.h>

#define NBINS 128

// Fixed problem shape: n = 8192 rows, d = 512 cols.
// Grid: 512 blocks = (cg in [0,8)) x (rg in [0,64)); bid = rg*8 + cg.
// Block (cg,rg) owns rows [rg*128, rg*128+128) x cols [cg*64, cg*64+64).
//
// ws layout (bytes) — every byte finalk reads is plain-stored by main_pass,
// so NO zero-init and NO atomics are needed:
//   [0,      131072)  float uslab[64][512]
//   [131072, 262144)  float vslab[64][512]
//   [262144, 264192)  float scalT[512]
//   [264192, 266240)  float scalP[512]
//   [266240, 268288)  float scalQ[512]
//   [268288, 268544)  float scalW[64]

__global__ __launch_bounds__(256) void main_pass(const float* __restrict__ x,
                                                 const int* __restrict__ tgt,
                                                 float* __restrict__ uslab,
                                                 float* __restrict__ vslab,
                                                 float* __restrict__ scalT,
                                                 float* __restrict__ scalP,
                                                 float* __restrict__ scalQ,
                                                 float* __restrict__ scalW) {
    const int tid  = threadIdx.x;
    const int bid  = blockIdx.x;
    const int cg   = bid & 7;     // column group (64 cols)
    const int rg   = bid >> 3;    // row group (128 rows)
    const int wave = tid >> 6, lane = tid & 63;

    __shared__ float xbuf[128 * 64];   // 32 KB tile
    __shared__ int   hw[4][NBINS];     // wave-private histograms
    __shared__ float crow[128];        // class counts for the block's rows
    __shared__ float ured[256 * 4];    // per-thread float4 u partials
    __shared__ float vred[256 * 4];
    __shared__ float redS[3][4];

    // ---- (1) stage the 32 KB tile: 8 async 16B direct-to-LDS copies/thread ----
    // elem16 = (k*4+wave)*64 + lane; row = elem16>>4, chunk = elem16&15
    const float* xb = x + (size_t)(rg * 128) * 512 + cg * 64;
    #pragma unroll
    for (int k = 0; k < 8; ++k) {
        const int e16   = (k * 4 + wave) * 64 + lane;
        const int row   = e16 >> 4;
        const int chunk = e16 & 15;
        const float* gptr = xb + (size_t)row * 512 + chunk * 4;
        float* lbase = &xbuf[(k * 4 + wave) * 256];   // wave-uniform; lane at +lane*16B
        __builtin_amdgcn_global_load_lds(
            (const __attribute__((address_space(1))) void*)gptr,
            (__attribute__((address_space(3))) void*)lbase, 16, 0, 0);
    }

    // ---- (2) targets: 8 int4/thread (all 8192), in flight with the staging ----
    int4 tv[8];
    const int4* t4 = (const int4*)tgt;
    #pragma unroll
    for (int k = 0; k < 8; ++k) tv[k] = t4[k * 256 + tid];

    // this block's 128 row labels (threads 0..127)
    const int mylab = (tid < 128) ? tgt[rg * 128 + tid] : 0;

    // ---- (3) wave-private LDS histogram (no barrier needed before atomics:
    //      each wave zeroes and fills only its own copy, in wave program order) ----
    hw[wave][lane] = 0;
    hw[wave][lane + 64] = 0;
    #pragma unroll
    for (int k = 0; k < 8; ++k) {
        atomicAdd(&hw[wave][tv[k].x & (NBINS - 1)], 1);
        atomicAdd(&hw[wave][tv[k].y & (NBINS - 1)], 1);
        atomicAdd(&hw[wave][tv[k].z & (NBINS - 1)], 1);
        atomicAdd(&hw[wave][tv[k].w & (NBINS - 1)], 1);
    }
    __syncthreads();   // drains staging vmcnt + all hist atomics

    if (tid < 128) {
        const int b = mylab & (NBINS - 1);
        crow[tid] = (float)(hw[0][b] + hw[1][b] + hw[2][b] + hw[3][b]);
    }
    __syncthreads();

    // ---- (4) accumulate: thread t -> col-quad q = t&15, rows g+16k, g = t>>4 ----
    const int q = tid & 15, g = tid >> 4;
    float t_acc = 0.f, p_acc = 0.f, q_acc = 0.f;
    float4 ua = make_float4(0.f, 0.f, 0.f, 0.f);
    float4 va = make_float4(0.f, 0.f, 0.f, 0.f);
    #pragma unroll
    for (int k = 0; k < 8; ++k) {
        const int r = g + 16 * k;
        const float c = crow[r];
        const float4 v = ((const float4*)xbuf)[r * 16 + q];
        const float sq = v.x*v.x + v.y*v.y + v.z*v.z + v.w*v.w;
        const float sm = v.x + v.y + v.z + v.w;
        t_acc += sq;
        p_acc += c * sq;
        q_acc += c * sm;
        ua.x += v.x;     ua.y += v.y;     ua.z += v.z;     ua.w += v.w;
        va.x += c * v.x; va.y += c * v.y; va.z += c * v.z; va.w += c * v.w;
    }

    // per-thread float4 partials to LDS
    ((float4*)ured)[tid] = ua;
    ((float4*)vred)[tid] = va;

    // scalar (T,P,Q) wave reduction (registers only) + park in LDS
    for (int off = 32; off > 0; off >>= 1) {
        t_acc += __shfl_down(t_acc, off);
        p_acc += __shfl_down(p_acc, off);
        q_acc += __shfl_down(q_acc, off);
    }
    if (lane == 0) { redS[0][wave] = t_acc; redS[1][wave] = p_acc; redS[2][wave] = q_acc; }
    __syncthreads();   // covers ured/vred and redS

    // ---- (5) column reduction + disjoint slab stores (no atomics) ----
    if (tid < 64) {
        const int cq = tid >> 2, ce = tid & 3;
        float su = 0.f, sv = 0.f;
        #pragma unroll
        for (int gg = 0; gg < 16; ++gg) {
            su += ured[(gg * 16 + cq) * 4 + ce];
            sv += vred[(gg * 16 + cq) * 4 + ce];
        }
        uslab[rg * 512 + cg * 64 + tid] = su;
        vslab[rg * 512 + cg * 64 + tid] = sv;
    }

    // Wsum (Sum of crow over the block's 128 rows) — wave 1, only cg==0 blocks
    if (wave == 1) {
        float w = crow[lane] + crow[lane + 64];
        for (int off = 32; off > 0; off >>= 1) w += __shfl_down(w, off);
        if (lane == 0 && cg == 0) scalW[rg] = w;
    }

    if (tid == 0) {
        scalT[bid] = redS[0][0] + redS[0][1] + redS[0][2] + redS[0][3];
        scalP[bid] = redS[1][0] + redS[1][1] + redS[1][2] + redS[1][3];
        scalQ[bid] = redS[2][0] + redS[2][1] + redS[2][2] + redS[2][3];
    }
}

// ---------------- final: reduce slabs + scalars, closed form ----------------
__global__ __launch_bounds__(256) void finalk(const float* __restrict__ uslab,
                                              const float* __restrict__ vslab,
                                              const float* __restrict__ scalT,
                                              const float* __restrict__ scalP,
                                              const float* __restrict__ scalQ,
                                              const float* __restrict__ scalW,
                                              int n, int d,
                                              float* __restrict__ out) {
    const int tid = threadIdx.x;
    // thread owns cols 2*tid, 2*tid+1
    float2 su = make_float2(0.f, 0.f), sv = make_float2(0.f, 0.f);
    const float2* u2 = (const float2*)uslab;
    const float2* v2 = (const float2*)vslab;
    #pragma unroll 8
    for (int rg = 0; rg < 64; ++rg) {
        float2 a = u2[rg * 256 + tid];
        float2 b = v2[rg * 256 + tid];
        su.x += a.x; su.y += a.y;
        sv.x += b.x; sv.y += b.y;
    }
    float uu = su.x * su.x + su.y * su.y;
    float us = su.x + su.y;
    float uv = su.x * sv.x + su.y * sv.y;
    float tt = scalT[tid] + scalT[tid + 256];
    float pp = scalP[tid] + scalP[tid + 256];
    float qq = scalQ[tid] + scalQ[tid + 256];
    float wc = (tid < 64) ? scalW[tid] : 0.f;

    for (int off = 32; off > 0; off >>= 1) {
        uu += __shfl_down(uu, off);
        us += __shfl_down(us, off);
        uv += __shfl_down(uv, off);
        tt += __shfl_down(tt, off);
        pp += __shfl_down(pp, off);
        qq += __shfl_down(qq, off);
        wc += __shfl_down(wc, off);
    }
    __shared__ float red[7][4];
    const int wave = tid >> 6, lane = tid & 63;
    if (lane == 0) {
        red[0][wave] = uu; red[1][wave] = us; red[2][wave] = uv;
        red[3][wave] = tt; red[4][wave] = pp; red[5][wave] = qq;
        red[6][wave] = wc;
    }
    __syncthreads();
    if (tid == 0) {
        double UU = 0, US = 0, UV = 0, T = 0, P = 0, Q = 0, WC = 0;
        for (int w = 0; w < 4; ++w) {
            UU += red[0][w]; US += red[1][w]; UV += red[2][w];
            T  += red[3][w]; P  += red[4][w]; Q  += red[5][w];
            WC += red[6][w];
        }
        const double N = (double)n, Dd = (double)d, eps = 1e-6;
        double Ssum = 2.0 * N * T - 2.0 * UU + N * N * Dd * eps * eps;
        double Anum = N * P + T * WC - 2.0 * UV
                    + 2.0 * eps * (N * Q - US * WC) + N * Dd * eps * eps * WC;
        double a = Anum / (N * WC);
        double b = (N * Ssum - Anum) / (N * (N * N - WC));
        out[0] = (float)(-a / b - b / a);
    }
}

extern "C" void kernel_launch(void* const* d_in, const int* in_sizes, int n_in,
                              void* d_out, int out_size, void* d_ws, size_t ws_size,
                              hipStream_t stream) {
    const float* x   = (const float*)d_in[0];
    const int*   tgt = (const int*)d_in[1];
    float*       out = (float*)d_out;

    const int n = in_sizes[1];          // 8192
    const int d = in_sizes[0] / n;      // 512

    char*  ws    = (char*)d_ws;
    float* uslab = (float*)ws;                       // 128 KB
    float* vslab = (float*)(ws + 131072);            // 128 KB
    float* scalT = (float*)(ws + 262144);            // 2 KB
    float* scalP = (float*)(ws + 264192);            // 2 KB
    float* scalQ = (float*)(ws + 266240);            // 2 KB
    float* scalW = (float*)(ws + 268288);            // 256 B

    main_pass<<<512, 256, 0, stream>>>(x, tgt, uslab, vslab, scalT, scalP, scalQ, scalW);
    finalk   <<<1,   256, 0, stream>>>(uslab, vslab, scalT, scalP, scalQ, scalW, n, d, out);
}